// Round 16
// baseline (179.502 us; speedup 1.0000x reference)
//
#include <hip/hip_runtime.h>
#include <hip/hip_bf16.h>

typedef __bf16 bf16;
typedef bf16 bf16x8 __attribute__((ext_vector_type(8)));
typedef bf16 bf16x4 __attribute__((ext_vector_type(4)));
typedef float f32x16 __attribute__((ext_vector_type(16)));

#define AS1 __attribute__((address_space(1)))
#define AS3 __attribute__((address_space(3)))

__device__ __forceinline__ void gload_lds16(const void* g, void* l) {
    __builtin_amdgcn_global_load_lds((const AS1 void*)g, (AS3 void*)l, 16, 0, 0);
}

// tanh(x) = 1 - 2/(e^{2x}+1); v_exp + v_rcp, clamp-free. rel-err ~1e-5.
__device__ __forceinline__ float tanh_fast(float x) {
    float e = __expf(2.0f * x);
    return fmaf(-2.0f, __builtin_amdgcn_rcpf(e + 1.0f), 1.0f);
}

// ---------------------------------------------------------------------------
// Kernel 1 (fused): blocks [0,8192): convert e1,e2 -> bf16 X=[e1|e2] and
// compute zs[m][c] = dot(e1[r]*e2[r], W[c])/2048, r = 2048*m + c.
// Blocks [8192,10240): V [4096][2048] f32 -> Vt [2048][4096] bf16 (B^T).
// ---------------------------------------------------------------------------
__global__ __launch_bounds__(256) void conv_fused(
    const float* __restrict__ e1, const float* __restrict__ e2,
    const float* __restrict__ W, const float* __restrict__ V,
    bf16* __restrict__ Xb, bf16* __restrict__ Vt, float* __restrict__ zs)
{
    __shared__ float tile[64][65];
    const int bid = blockIdx.x;
    const int t = threadIdx.x;

    if (bid < 8192) {
        const int r = bid;              // row 0..8191
        const int c = r & 2047, m = r >> 11;
        const size_t rb = (size_t)r * 2048;

        const float4* p1 = (const float4*)(e1 + rb) + t * 2;
        const float4* p2 = (const float4*)(e2 + rb) + t * 2;
        const float4* pw = (const float4*)(W + (size_t)c * 2048) + t * 2;
        float4 a0 = p1[0], a1 = p1[1];
        float4 b0 = p2[0], b1 = p2[1];
        float4 w0 = pw[0], w1 = pw[1];

        float dot = a0.x*b0.x*w0.x + a0.y*b0.y*w0.y + a0.z*b0.z*w0.z + a0.w*b0.w*w0.w
                  + a1.x*b1.x*w1.x + a1.y*b1.y*w1.y + a1.z*b1.z*w1.z + a1.w*b1.w*w1.w;

        bf16x8 xa, xb;
        xa[0]=(bf16)a0.x; xa[1]=(bf16)a0.y; xa[2]=(bf16)a0.z; xa[3]=(bf16)a0.w;
        xa[4]=(bf16)a1.x; xa[5]=(bf16)a1.y; xa[6]=(bf16)a1.z; xa[7]=(bf16)a1.w;
        xb[0]=(bf16)b0.x; xb[1]=(bf16)b0.y; xb[2]=(bf16)b0.z; xb[3]=(bf16)b0.w;
        xb[4]=(bf16)b1.x; xb[5]=(bf16)b1.y; xb[6]=(bf16)b1.z; xb[7]=(bf16)b1.w;

        *(bf16x8*)(Xb + (size_t)r * 4096 + t * 8)        = xa;
        *(bf16x8*)(Xb + (size_t)r * 4096 + 2048 + t * 8) = xb;

        #pragma unroll
        for (int off = 32; off; off >>= 1) dot += __shfl_xor(dot, off);
        float* red = &tile[0][0];
        if ((t & 63) == 0) red[t >> 6] = dot;
        __syncthreads();
        if (t == 0) zs[m * 2048 + c] = (red[0]+red[1]+red[2]+red[3]) * (1.0f/2048.0f);
    } else {
        const int vb = bid - 8192;
        const int k0 = (vb >> 5) * 64;  // 64 k-tiles
        const int c0 = (vb & 31) * 64;  // 32 c-tiles
        const int rr = t >> 4;
        const int cc = (t & 15) * 4;

        #pragma unroll
        for (int r4 = 0; r4 < 4; ++r4) {
            int row = r4 * 16 + rr;
            float4 v = *(const float4*)(V + (size_t)(k0 + row) * 2048 + c0 + cc);
            tile[row][cc + 0] = v.x; tile[row][cc + 1] = v.y;
            tile[row][cc + 2] = v.z; tile[row][cc + 3] = v.w;
        }
        __syncthreads();
        #pragma unroll
        for (int r4 = 0; r4 < 4; ++r4) {
            int crow = r4 * 16 + rr;
            bf16x4 o;
            o[0] = (bf16)tile[cc + 0][crow];
            o[1] = (bf16)tile[cc + 1][crow];
            o[2] = (bf16)tile[cc + 2][crow];
            o[3] = (bf16)tile[cc + 3][crow];
            *(bf16x4*)(Vt + (size_t)(c0 + crow) * 4096 + k0 + cc) = o;
        }
    }
}

// ---------------------------------------------------------------------------
// Kernel 2: 256x256-tile GEMM, frozen 2-barrier K-loop (r12), MFMA shape
// swapped to 32x32x16 (r16): measured 13-15% faster per FLOP (m06/m119) and
// half the MFMA instruction count. Dataflow/registers/LDS unchanged:
// quadrants qm,qn of the 128x64 wave tile; per quadrant 2 row-frags x 4
// k-slices of 32x32x16; aA (32 reg) reused across 2 quads, bB0/bB1 (32 reg)
// resident; acc = 8 x f32x16 = 128.
// Operand map (K-doubling pattern, validated at 16x16 by r1-r15):
//   A[row][k]: row = lane&31, k = (lane>>5)*8 + e  -> 16B read at
//   phys = R*128 + ((ks*32 + (lane>>5)*16) ^ ((R&7)<<4)); quarter-wave
//   groups read 16 consecutive rows -> 2-way bank aliasing (free).
// C/D (m74/m101): col = lane&31, row = (reg&3) + 8*(reg>>2) + 4*(lane>>5);
// row % 4 == reg&3 -> zs[p%4] epilogue indexing exact.
// XCD A-reuse mapping (r11), source-side swizzle (rule #21), fast-tanh
// row-major epilogue (r12).
// ---------------------------------------------------------------------------
__global__ __launch_bounds__(512, 2) void gemm_ep(
    const bf16* __restrict__ Xb, const bf16* __restrict__ Vt,
    const float* __restrict__ zs, const float* __restrict__ bias,
    float* __restrict__ out)
{
    extern __shared__ char smem[];     // 131072 bytes
    const int tid  = threadIdx.x;
    const int lane = tid & 63;
    const int wid  = tid >> 6;
    const int wr = wid >> 2, wc = wid & 3;
    const int mtile = blockIdx.x & 31;   // 32 row tiles (A-reuse XCD mapping)
    const int ntile = blockIdx.x >> 5;   // 8 col tiles
    const int row0 = mtile * 256, col0 = ntile * 256;

    const int srow = tid >> 3;                               // 0..63
    const int scb  = ((tid & 7) * 16) ^ ((srow & 7) << 4);   // swizzled byte col
    const bf16* Abase = Xb + (size_t)(row0 + srow) * 4096 + (scb >> 1);
    const bf16* Bbase = Vt + (size_t)(col0 + srow) * 4096 + (scb >> 1);

    const int l31 = lane & 31;
    const int lgb = (lane >> 5) * 16;   // lane-group k-slice byte offset

    f32x16 acc[2][2][2] = {};     // [qm][qn][i]
    bf16x8 aA[2][4];              // current A half: [i][ks]
    bf16x8 bB0[4], bB1[4];        // B halves: [ks], resident whole K-step

    auto stage = [&](int c, int kt) {
        char* Al = smem + c * 65536 + tid * 16;
        char* Bl = smem + c * 65536 + 32768 + tid * 16;
        const bf16* Ag = Abase + (size_t)kt * 64;
        const bf16* Bg = Bbase + (size_t)kt * 64;
        #pragma unroll
        for (int r = 0; r < 4; ++r) gload_lds16(Ag + (size_t)r * 262144, Al + r * 8192);
        #pragma unroll
        for (int r = 0; r < 4; ++r) gload_lds16(Bg + (size_t)r * 262144, Bl + r * 8192);
    };

    auto ldsA = [&](const char* Ab, int qm, int i, int ks) -> bf16x8 {
        const int R = wr * 128 + qm * 64 + i * 32 + l31;
        const int cb = ks * 32 + lgb;
        return *(const bf16x8*)(Ab + R * 128 + (cb ^ ((R & 7) << 4)));
    };
    auto ldsB = [&](const char* Bb, int qn, int ks) -> bf16x8 {
        const int R = wc * 64 + qn * 32 + l31;
        const int cb = ks * 32 + lgb;
        return *(const bf16x8*)(Bb + R * 128 + (cb ^ ((R & 7) << 4)));
    };
    auto quad = [&](f32x16 (&a)[2], bf16x8 (&bv)[4]) {
        __builtin_amdgcn_s_setprio(1);
        #pragma unroll
        for (int ks = 0; ks < 4; ++ks)
            #pragma unroll
            for (int i = 0; i < 2; ++i)
                a[i] = __builtin_amdgcn_mfma_f32_32x32x16_bf16(
                    aA[i][ks], bv[ks], a[i], 0, 0, 0);
        __builtin_amdgcn_s_setprio(0);
    };

    auto window1 = [&](int c) {
        const char* Ab = smem + c * 65536;
        const char* Bb = smem + c * 65536 + 32768;
        #pragma unroll
        for (int i = 0; i < 2; ++i)
            #pragma unroll
            for (int ks = 0; ks < 4; ++ks) aA[i][ks] = ldsA(Ab, 0, i, ks);
        #pragma unroll
        for (int ks = 0; ks < 4; ++ks) bB0[ks] = ldsB(Bb, 0, ks);
        quad(acc[0][0], bB0);                      // q00
        #pragma unroll
        for (int ks = 0; ks < 4; ++ks) bB1[ks] = ldsB(Bb, 1, ks);
        quad(acc[0][1], bB1);                      // q01
        #pragma unroll
        for (int i = 0; i < 2; ++i)
            #pragma unroll
            for (int ks = 0; ks < 4; ++ks) aA[i][ks] = ldsA(Ab, 1, i, ks);
        quad(acc[1][1], bB1);                      // q11
    };

    // prologue: tiles 0,1 in flight; tile 0 guaranteed landed
    stage(0, 0);
    stage(1, 1);
    asm volatile("s_waitcnt vmcnt(8)" ::: "memory");
    __builtin_amdgcn_s_barrier();

    #pragma unroll 2
    for (int t = 0; t < 62; ++t) {
        const int c = t & 1;
        window1(c);
        __builtin_amdgcn_s_barrier();          // all buf-c reads complete
        stage(c, t + 2);                       // overwrite buf c with tile t+2
        quad(acc[1][0], bB0);                  // q10 (aA holds A half 1)
        asm volatile("s_waitcnt vmcnt(8)" ::: "memory");  // tile t+1 landed
        __builtin_amdgcn_s_barrier();
    }
    // t = 62 (buf 0): no stage; drain tile 63's loads
    window1(0);
    __builtin_amdgcn_s_barrier();
    quad(acc[1][0], bB0);
    asm volatile("s_waitcnt vmcnt(0)" ::: "memory");
    __builtin_amdgcn_s_barrier();
    // t = 63 (buf 1): final K-step, no staging, no waits
    window1(1);
    quad(acc[1][0], bB0);

    // epilogue: out = tanh(acc + zs[p%4][c] + bias[c])
    // C/D (m74/m101): col = lane&31, row = (reg&3)+8*(reg>>2)+4*(lane>>5);
    // p % 4 == reg&3. Row-major store order: one inst = 2 rows x 128B.
    const int lg4 = (lane >> 5) * 4;
    float zb[2][4];
    #pragma unroll
    for (int qn = 0; qn < 2; ++qn) {
        const int ccol = col0 + wc * 64 + qn * 32 + l31;
        const float bb = bias[ccol];
        #pragma unroll
        for (int q = 0; q < 4; ++q) zb[qn][q] = zs[q * 2048 + ccol] + bb;
    }
    #pragma unroll
    for (int qm = 0; qm < 2; ++qm)
        #pragma unroll
        for (int i = 0; i < 2; ++i)
            #pragma unroll
            for (int rg = 0; rg < 4; ++rg)
                #pragma unroll
                for (int q = 0; q < 4; ++q) {
                    const int reg = rg * 4 + q;
                    float* orow = out + (size_t)(row0 + wr * 128 + qm * 64
                                                 + i * 32 + rg * 8 + lg4 + q) * 2048
                                      + col0 + wc * 64 + l31;
                    #pragma unroll
                    for (int qn = 0; qn < 2; ++qn)
                        orow[qn * 32] = tanh_fast(acc[qm][qn][i][reg] + zb[qn][q]);
                }
}

// ---------------------------------------------------------------------------
extern "C" void kernel_launch(void* const* d_in, const int* in_sizes, int n_in,
                              void* d_out, int out_size, void* d_ws, size_t ws_size,
                              hipStream_t stream) {
    const float* e1 = (const float*)d_in[0];   // (8192, 2048)
    const float* e2 = (const float*)d_in[1];   // (8192, 2048)
    const float* W  = (const float*)d_in[2];   // (2048, 2048)
    const float* V  = (const float*)d_in[3];   // (4096, 2048)
    const float* b  = (const float*)d_in[4];   // (2048,)
    float* out = (float*)d_out;                // (8192, 2048) f32

    char* ws = (char*)d_ws;
    bf16*  Xb = (bf16*)ws;                                  // 64 MiB
    bf16*  Vt = (bf16*)(ws + (size_t)64 * 1024 * 1024);     // 16 MiB
    float* zs = (float*)(ws + (size_t)80 * 1024 * 1024);    // 32 KiB

    conv_fused<<<10240, 256, 0, stream>>>(e1, e2, W, V, Xb, Vt, zs);

    hipFuncSetAttribute((const void*)gemm_ep,
                        hipFuncAttributeMaxDynamicSharedMemorySize, 131072);
    gemm_ep<<<256, 512, 131072, stream>>>(Xb, Vt, zs, b, out);
}

// Round 17
// 161.446 us; speedup vs baseline: 1.1118x; 1.1118x over previous
//
#include <hip/hip_runtime.h>
#include <hip/hip_bf16.h>

typedef __bf16 bf16;
typedef bf16 bf16x8 __attribute__((ext_vector_type(8)));
typedef bf16 bf16x4 __attribute__((ext_vector_type(4)));
typedef float f32x4 __attribute__((ext_vector_type(4)));

#define AS1 __attribute__((address_space(1)))
#define AS3 __attribute__((address_space(3)))

__device__ __forceinline__ void gload_lds16(const void* g, void* l) {
    __builtin_amdgcn_global_load_lds((const AS1 void*)g, (AS3 void*)l, 16, 0, 0);
}

// tanh(x) = 1 - 2/(e^{2x}+1); v_exp + v_rcp, clamp-free. rel-err ~1e-5.
__device__ __forceinline__ float tanh_fast(float x) {
    float e = __expf(2.0f * x);
    return fmaf(-2.0f, __builtin_amdgcn_rcpf(e + 1.0f), 1.0f);
}

// ---------------------------------------------------------------------------
// Kernel 1 (fused): blocks [0,8192): convert e1,e2 -> bf16 X=[e1|e2] and
// compute zs[m][c] = dot(e1[r]*e2[r], W[c])/2048, r = 2048*m + c.
// Blocks [8192,10240): V [4096][2048] f32 -> Vt [2048][4096] bf16 (B^T).
// Runs at ~95% of achievable HBM BW (~52us for 212MB).
// ---------------------------------------------------------------------------
__global__ __launch_bounds__(256) void conv_fused(
    const float* __restrict__ e1, const float* __restrict__ e2,
    const float* __restrict__ W, const float* __restrict__ V,
    bf16* __restrict__ Xb, bf16* __restrict__ Vt, float* __restrict__ zs)
{
    __shared__ float tile[64][65];
    const int bid = blockIdx.x;
    const int t = threadIdx.x;

    if (bid < 8192) {
        const int r = bid;              // row 0..8191
        const int c = r & 2047, m = r >> 11;
        const size_t rb = (size_t)r * 2048;

        const float4* p1 = (const float4*)(e1 + rb) + t * 2;
        const float4* p2 = (const float4*)(e2 + rb) + t * 2;
        const float4* pw = (const float4*)(W + (size_t)c * 2048) + t * 2;
        float4 a0 = p1[0], a1 = p1[1];
        float4 b0 = p2[0], b1 = p2[1];
        float4 w0 = pw[0], w1 = pw[1];

        float dot = a0.x*b0.x*w0.x + a0.y*b0.y*w0.y + a0.z*b0.z*w0.z + a0.w*b0.w*w0.w
                  + a1.x*b1.x*w1.x + a1.y*b1.y*w1.y + a1.z*b1.z*w1.z + a1.w*b1.w*w1.w;

        bf16x8 xa, xb;
        xa[0]=(bf16)a0.x; xa[1]=(bf16)a0.y; xa[2]=(bf16)a0.z; xa[3]=(bf16)a0.w;
        xa[4]=(bf16)a1.x; xa[5]=(bf16)a1.y; xa[6]=(bf16)a1.z; xa[7]=(bf16)a1.w;
        xb[0]=(bf16)b0.x; xb[1]=(bf16)b0.y; xb[2]=(bf16)b0.z; xb[3]=(bf16)b0.w;
        xb[4]=(bf16)b1.x; xb[5]=(bf16)b1.y; xb[6]=(bf16)b1.z; xb[7]=(bf16)b1.w;

        *(bf16x8*)(Xb + (size_t)r * 4096 + t * 8)        = xa;
        *(bf16x8*)(Xb + (size_t)r * 4096 + 2048 + t * 8) = xb;

        #pragma unroll
        for (int off = 32; off; off >>= 1) dot += __shfl_xor(dot, off);
        float* red = &tile[0][0];
        if ((t & 63) == 0) red[t >> 6] = dot;
        __syncthreads();
        if (t == 0) zs[m * 2048 + c] = (red[0]+red[1]+red[2]+red[3]) * (1.0f/2048.0f);
    } else {
        const int vb = bid - 8192;
        const int k0 = (vb >> 5) * 64;  // 64 k-tiles
        const int c0 = (vb & 31) * 64;  // 32 c-tiles
        const int rr = t >> 4;
        const int cc = (t & 15) * 4;

        #pragma unroll
        for (int r4 = 0; r4 < 4; ++r4) {
            int row = r4 * 16 + rr;
            float4 v = *(const float4*)(V + (size_t)(k0 + row) * 2048 + c0 + cc);
            tile[row][cc + 0] = v.x; tile[row][cc + 1] = v.y;
            tile[row][cc + 2] = v.z; tile[row][cc + 3] = v.w;
        }
        __syncthreads();
        #pragma unroll
        for (int r4 = 0; r4 < 4; ++r4) {
            int crow = r4 * 16 + rr;
            bf16x4 o;
            o[0] = (bf16)tile[cc + 0][crow];
            o[1] = (bf16)tile[cc + 1][crow];
            o[2] = (bf16)tile[cc + 2][crow];
            o[3] = (bf16)tile[cc + 3][crow];
            *(bf16x4*)(Vt + (size_t)(c0 + crow) * 4096 + k0 + cc) = o;
        }
    }
}

// ---------------------------------------------------------------------------
// Kernel 2: 256x256-tile GEMM, 2-barriers-per-K-step (r4/r12 schedule — best
// measured across 16 rounds; issue-bound, not traffic-bound). K-loop frozen:
// - 16x16x32 MFMA (r16: 32x32x16 is structurally 4-way bank-conflicted in a
//   gload_lds-linear layout — 1.26e7 conflicts measured, net regression).
// - 2 waves/SIMD caps regs at 256/wave: acc(128)+aA(32)+bB(32) leaves no
//   room for deeper pipelining (r5/r13 spilled; r14 added unhidden work).
// XCD A-reuse mapping: mtile=bid&31, ntile=bid>>5 (FETCH 98.6MB ~ ideal).
// T2 swizzle: phys byte = R*128 + (cb ^ ((R&7)<<4)); source inverse-swizzled
// (rule #21); conflicts measured 0. Epilogue: fast tanh (exp+rcp) +
// row-major stores (WRITE 67MB ~ ideal).
// ---------------------------------------------------------------------------
__global__ __launch_bounds__(512, 2) void gemm_ep(
    const bf16* __restrict__ Xb, const bf16* __restrict__ Vt,
    const float* __restrict__ zs, const float* __restrict__ bias,
    float* __restrict__ out)
{
    extern __shared__ char smem[];     // 131072 bytes
    const int tid  = threadIdx.x;
    const int lane = tid & 63;
    const int wid  = tid >> 6;
    const int wr = wid >> 2, wc = wid & 3;
    const int mtile = blockIdx.x & 31;   // 32 row tiles (A-reuse XCD mapping)
    const int ntile = blockIdx.x >> 5;   // 8 col tiles
    const int row0 = mtile * 256, col0 = ntile * 256;

    const int srow = tid >> 3;                               // 0..63
    const int scb  = ((tid & 7) * 16) ^ ((srow & 7) << 4);   // swizzled byte col
    const bf16* Abase = Xb + (size_t)(row0 + srow) * 4096 + (scb >> 1);
    const bf16* Bbase = Vt + (size_t)(col0 + srow) * 4096 + (scb >> 1);

    const int lr  = lane & 15;
    const int lkb = (lane >> 4) * 16;

    f32x4 acc[2][2][4][2] = {};   // [qm][qn][i][j]
    bf16x8 aA[4][2];              // current A half (reused q00/q01 -> q11/q10)
    bf16x8 bB[2][2][2];           // [qn][j][ks], both halves live all K-step

    auto stage = [&](int c, int kt) {
        char* Al = smem + c * 65536 + tid * 16;
        char* Bl = smem + c * 65536 + 32768 + tid * 16;
        const bf16* Ag = Abase + (size_t)kt * 64;
        const bf16* Bg = Bbase + (size_t)kt * 64;
        #pragma unroll
        for (int r = 0; r < 4; ++r) gload_lds16(Ag + (size_t)r * 262144, Al + r * 8192);
        #pragma unroll
        for (int r = 0; r < 4; ++r) gload_lds16(Bg + (size_t)r * 262144, Bl + r * 8192);
    };

    auto ldsA = [&](const char* Ab, int qm, int i, int ks) -> bf16x8 {
        const int R = wr * 128 + qm * 64 + i * 16 + lr;
        const int cb = ks * 64 + lkb;
        return *(const bf16x8*)(Ab + R * 128 + (cb ^ ((R & 7) << 4)));
    };
    auto ldsB = [&](const char* Bb, int qn, int j, int ks) -> bf16x8 {
        const int R = wc * 64 + qn * 32 + j * 16 + lr;
        const int cb = ks * 64 + lkb;
        return *(const bf16x8*)(Bb + R * 128 + (cb ^ ((R & 7) << 4)));
    };

    auto window1 = [&](int c) {
        const char* Ab = smem + c * 65536;
        const char* Bb = smem + c * 65536 + 32768;
        #pragma unroll
        for (int i = 0; i < 4; ++i) { aA[i][0] = ldsA(Ab, 0, i, 0); aA[i][1] = ldsA(Ab, 0, i, 1); }
        #pragma unroll
        for (int j = 0; j < 2; ++j) { bB[0][j][0] = ldsB(Bb, 0, j, 0); bB[0][j][1] = ldsB(Bb, 0, j, 1); }
        __builtin_amdgcn_s_setprio(1);
        #pragma unroll
        for (int ks = 0; ks < 2; ++ks)
            #pragma unroll
            for (int i = 0; i < 4; ++i)
                #pragma unroll
                for (int j = 0; j < 2; ++j)
                    acc[0][0][i][j] = __builtin_amdgcn_mfma_f32_16x16x32_bf16(
                        aA[i][ks], bB[0][j][ks], acc[0][0][i][j], 0, 0, 0);
        __builtin_amdgcn_s_setprio(0);
        #pragma unroll
        for (int j = 0; j < 2; ++j) { bB[1][j][0] = ldsB(Bb, 1, j, 0); bB[1][j][1] = ldsB(Bb, 1, j, 1); }
        __builtin_amdgcn_s_setprio(1);
        #pragma unroll
        for (int ks = 0; ks < 2; ++ks)
            #pragma unroll
            for (int i = 0; i < 4; ++i)
                #pragma unroll
                for (int j = 0; j < 2; ++j)
                    acc[0][1][i][j] = __builtin_amdgcn_mfma_f32_16x16x32_bf16(
                        aA[i][ks], bB[1][j][ks], acc[0][1][i][j], 0, 0, 0);
        __builtin_amdgcn_s_setprio(0);
        #pragma unroll
        for (int i = 0; i < 4; ++i) { aA[i][0] = ldsA(Ab, 1, i, 0); aA[i][1] = ldsA(Ab, 1, i, 1); }
        __builtin_amdgcn_s_setprio(1);
        #pragma unroll
        for (int ks = 0; ks < 2; ++ks)
            #pragma unroll
            for (int i = 0; i < 4; ++i)
                #pragma unroll
                for (int j = 0; j < 2; ++j)
                    acc[1][1][i][j] = __builtin_amdgcn_mfma_f32_16x16x32_bf16(
                        aA[i][ks], bB[1][j][ks], acc[1][1][i][j], 0, 0, 0);
        __builtin_amdgcn_s_setprio(0);
    };

    auto mfma_q10 = [&]() {
        __builtin_amdgcn_s_setprio(1);
        #pragma unroll
        for (int ks = 0; ks < 2; ++ks)
            #pragma unroll
            for (int i = 0; i < 4; ++i)
                #pragma unroll
                for (int j = 0; j < 2; ++j)
                    acc[1][0][i][j] = __builtin_amdgcn_mfma_f32_16x16x32_bf16(
                        aA[i][ks], bB[0][j][ks], acc[1][0][i][j], 0, 0, 0);
        __builtin_amdgcn_s_setprio(0);
    };

    // prologue: tiles 0,1 in flight; tile 0 guaranteed landed
    stage(0, 0);
    stage(1, 1);
    asm volatile("s_waitcnt vmcnt(8)" ::: "memory");
    __builtin_amdgcn_s_barrier();

    #pragma unroll 2
    for (int t = 0; t < 62; ++t) {
        const int c = t & 1;
        window1(c);
        __builtin_amdgcn_s_barrier();          // all buf-c reads complete
        stage(c, t + 2);                       // overwrite buf c with tile t+2
        mfma_q10();
        asm volatile("s_waitcnt vmcnt(8)" ::: "memory");  // tile t+1 landed
        __builtin_amdgcn_s_barrier();
    }
    // t = 62 (buf 0): no stage; drain tile 63's loads
    window1(0);
    __builtin_amdgcn_s_barrier();
    mfma_q10();
    asm volatile("s_waitcnt vmcnt(0)" ::: "memory");
    __builtin_amdgcn_s_barrier();
    // t = 63 (buf 1): final K-step, no staging, no waits
    window1(1);
    mfma_q10();

    // epilogue: out = tanh(acc + zs[p%4][c] + bias[c])
    // C/D layout (m89): col = lane&15, row = (lane>>4)*4 + q; p%4 == q here.
    // Pre-gather zs+bias (16 regs), then store row-major: (qm,i,q) outer,
    // (qn,j) inner -> consecutive insts fill 128 contiguous cols of one row.
    const int lq = lane >> 4;
    float zb[2][2][4];
    #pragma unroll
    for (int qn = 0; qn < 2; ++qn)
        #pragma unroll
        for (int j = 0; j < 2; ++j) {
            const int ccol = col0 + wc * 64 + qn * 32 + j * 16 + lr;
            const float bb = bias[ccol];
            #pragma unroll
            for (int q = 0; q < 4; ++q) zb[qn][j][q] = zs[q * 2048 + ccol] + bb;
        }
    #pragma unroll
    for (int qm = 0; qm < 2; ++qm)
        #pragma unroll
        for (int i = 0; i < 4; ++i)
            #pragma unroll
            for (int q = 0; q < 4; ++q) {
                float* orow = out + (size_t)(row0 + wr * 128 + qm * 64 + i * 16
                                             + lq * 4 + q) * 2048
                                  + col0 + wc * 64 + lr;
                #pragma unroll
                for (int qn = 0; qn < 2; ++qn)
                    #pragma unroll
                    for (int j = 0; j < 2; ++j)
                        orow[qn * 32 + j * 16] =
                            tanh_fast(acc[qm][qn][i][j][q] + zb[qn][j][q]);
            }
}

// ---------------------------------------------------------------------------
extern "C" void kernel_launch(void* const* d_in, const int* in_sizes, int n_in,
                              void* d_out, int out_size, void* d_ws, size_t ws_size,
                              hipStream_t stream) {
    const float* e1 = (const float*)d_in[0];   // (8192, 2048)
    const float* e2 = (const float*)d_in[1];   // (8192, 2048)
    const float* W  = (const float*)d_in[2];   // (2048, 2048)
    const float* V  = (const float*)d_in[3];   // (4096, 2048)
    const float* b  = (const float*)d_in[4];   // (2048,)
    float* out = (float*)d_out;                // (8192, 2048) f32

    char* ws = (char*)d_ws;
    bf16*  Xb = (bf16*)ws;                                  // 64 MiB
    bf16*  Vt = (bf16*)(ws + (size_t)64 * 1024 * 1024);     // 16 MiB
    float* zs = (float*)(ws + (size_t)80 * 1024 * 1024);    // 32 KiB

    conv_fused<<<10240, 256, 0, stream>>>(e1, e2, W, V, Xb, Vt, zs);

    hipFuncSetAttribute((const void*)gemm_ep,
                        hipFuncAttributeMaxDynamicSharedMemorySize, 131072);
    gemm_ep<<<256, 512, 131072, stream>>>(Xb, Vt, zs, b, out);
}